// Round 1
// 345.709 us; speedup vs baseline: 1.0026x; 1.0026x over previous
//
#include <hip/hip_runtime.h>
#include <math.h>

#define NROWS 4096
#define DDIM  1024

typedef __attribute__((ext_vector_type(8))) short short8;
typedef __attribute__((ext_vector_type(4))) float f32x4;

// ---------- bf16 helpers (manual RNE) ----------
__device__ __forceinline__ ushort f2bf(float v) {
  union { float f; uint32_t u; } c; c.f = v;
  uint32_t u = c.u;
  uint32_t lsb = (u >> 16) & 1u;
  u += 0x7fffu + lsb;
  return (ushort)(u >> 16);
}
__device__ __forceinline__ float bf2f(ushort h) {
  union { uint32_t u; float f; } c; c.u = ((uint32_t)h) << 16;
  return c.f;
}

// ---------- packed-fragment layout ----------
// Matrix [R][C] bf16 stored as 16x32 tiles of 1KB: tile T = (r>>4)*ldt + (c>>5)
// (ldt = C/32). Within tile: ushort index = ((c>>3)&3)*128 + (r&15)*8 + (c&7).
// A wave's MFMA fragment (rows r0..r0+15, cols c0..c0+31) is then the 1KB at
// T*512, lane ln reading 16B at T*512 + ln*8  (ln = quad*16 + l16).
__device__ __forceinline__ size_t pidx(int r, int c, int ldt) {
  return ((size_t)((r >> 4) * ldt + (c >> 5))) * 512 +
         ((c >> 3) & 3) * 128 + (r & 15) * 8 + (c & 7);
}

// ---------- prep: split x + transpose/split 3 weights, ALL outputs packed ----------
__global__ __launch_bounds__(256) void prep(const float* __restrict__ x,
                                            const float* __restrict__ wq,
                                            const float* __restrict__ wk,
                                            const float* __restrict__ wv,
                                            ushort* Xh, ushort* Xl,
                                            ushort* Wqh, ushort* Wql,
                                            ushort* Wkh, ushort* Wkl, ushort* Wvh) {
  __shared__ float tl[32][33];
  const int b = blockIdx.x, t = threadIdx.x;
  if (b < 1024) {
    const float4* src = (const float4*)x;
#pragma unroll
    for (int r = 0; r < 4; ++r) {
      int i = b * 1024 + r * 256 + t;       // float4 index over [4096][256]
      int row = i >> 8;
      int c = (i & 255) << 2;               // 4-aligned column
      float4 v = src[i];
      ushort4 h, l;
      h.x = f2bf(v.x); l.x = f2bf(v.x - bf2f(h.x));
      h.y = f2bf(v.y); l.y = f2bf(v.y - bf2f(h.y));
      h.z = f2bf(v.z); l.z = f2bf(v.z - bf2f(h.z));
      h.w = f2bf(v.w); l.w = f2bf(v.w - bf2f(h.w));
      size_t o = pidx(row, c, DDIM / 32);   // (c&7)∈{0,4} -> 8B aligned
      *(ushort4*)(Xh + o) = h;
      *(ushort4*)(Xl + o) = l;
    }
  } else {
    const int z = (b - 1024) >> 10;
    const int tile = (b - 1024) & 1023;
    const float* src = z == 0 ? wq : (z == 1 ? wk : wv);
    ushort* dh = z == 0 ? Wqh : (z == 1 ? Wkh : Wvh);
    ushort* dl = z == 0 ? Wql : (z == 1 ? Wkl : nullptr);
    const int r0 = (tile >> 5) * 32;
    const int c0 = (tile & 31) * 32;
    const int tx = t & 31, ty = t >> 5;
    for (int i = ty; i < 32; i += 8)
      tl[i][tx] = src[(size_t)(r0 + i) * DDIM + c0 + tx];
    __syncthreads();
    for (int i = ty; i < 32; i += 8) {
      float v = tl[tx][i];                  // = W[r0+tx][c0+i]
      ushort h = f2bf(v);
      size_t o = pidx(c0 + i, r0 + tx, DDIM / 32);  // W^T[c0+i][r0+tx], packed
      dh[o] = h;
      if (dl) dl[o] = f2bf(v - bf2f(h));
    }
  }
}

// ---------- LDS-free, barrier-free direct packed-fragment GEMM core ----------
// C[m0..m0+127][n0..n0+127] (+=) A(packed, K=KT*32) * B(packed, K=KT*32)^T-style
// (both operands stored rows-by-K; MFMA does row(A) . row(B)).
template <bool SPLIT, int KT>
__device__ __forceinline__ void direct_gemm(const ushort* __restrict__ Ah,
                                            const ushort* __restrict__ Al,
                                            const ushort* __restrict__ Bh,
                                            const ushort* __restrict__ Bl,
                                            int m0, int n0, f32x4 (*acc)[4]) {
  const int t = threadIdx.x;
  const int wv = t >> 6, ln = t & 63;
  const int arb = (wv >> 1) * 64, crb = (wv & 1) * 64;
  const int ra = (m0 + arb) >> 4;           // A tile-row base (frags ra..ra+3)
  const int rb = (n0 + crb) >> 4;
  const size_t ts = (size_t)KT * 512;       // tile-row stride in ushorts

  size_t baseA[4], baseB[4];
#pragma unroll
  for (int i = 0; i < 4; ++i) baseA[i] = (size_t)(ra + i) * ts + ln * 8;
#pragma unroll
  for (int j = 0; j < 4; ++j) baseB[j] = (size_t)(rb + j) * ts + ln * 8;

#pragma unroll 2
  for (int s = 0; s < KT; ++s) {
    short8 ah[4], al[4];
#pragma unroll
    for (int i = 0; i < 4; ++i) {
      size_t o = baseA[i] + (size_t)s * 512;
      ah[i] = *(const short8*)(Ah + o);
      if constexpr (SPLIT) al[i] = *(const short8*)(Al + o);
    }
#pragma unroll
    for (int j = 0; j < 4; ++j) {
      size_t o = baseB[j] + (size_t)s * 512;
      short8 bh = *(const short8*)(Bh + o);
#pragma unroll
      for (int i = 0; i < 4; ++i)
        acc[i][j] = __builtin_amdgcn_mfma_f32_16x16x32_bf16(ah[i], bh, acc[i][j], 0, 0, 0);
      if constexpr (SPLIT) {
        short8 bl = *(const short8*)(Bl + o);
#pragma unroll
        for (int i = 0; i < 4; ++i) {
          acc[i][j] = __builtin_amdgcn_mfma_f32_16x16x32_bf16(ah[i], bl, acc[i][j], 0, 0, 0);
          acc[i][j] = __builtin_amdgcn_mfma_f32_16x16x32_bf16(al[i], bh, acc[i][j], 0, 0, 0);
        }
      }
    }
  }
}

// ---------- fused QKV: all three GEMMs direct-packed, no LDS, no barriers ----------
__global__ __launch_bounds__(256) void gemm_qkv(const ushort* __restrict__ Xh,
                                                const ushort* __restrict__ Xl,
                                                const ushort* __restrict__ Wqh, const ushort* __restrict__ Wql,
                                                const ushort* __restrict__ Wkh, const ushort* __restrict__ Wkl,
                                                const ushort* __restrict__ Wvh,
                                                ushort* Qh, ushort* Ql, ushort* Kh, ushort* Kl, ushort* Vt) {
  const int which = blockIdx.x % 3;
  const int g = blockIdx.x / 3;              // 0..7 (d_out slice)
  const int by = blockIdx.y;                 // 0..31
  const int t = threadIdx.x;
  const int wv = t >> 6, ln = t & 63;
  const int quad = ln >> 4, l16 = ln & 15;

  f32x4 acc[4][4];
#pragma unroll
  for (int i = 0; i < 4; ++i)
#pragma unroll
    for (int j = 0; j < 4; ++j) acc[i][j] = (f32x4){0.f, 0.f, 0.f, 0.f};

  if (which == 2) {
    // Vt[d][kv] = sum_k WvT[d][k] * X[kv][k]  (= V[kv][d]) -> packed, ldt = 4096/32
    const int m0 = g * 128;                  // d over 1024
    const int n0 = by * 128;                 // kv over 4096
    direct_gemm<false, DDIM / 32>(Wvh, nullptr, Xh, nullptr, m0, n0, acc);
#pragma unroll
    for (int i = 0; i < 4; ++i)
#pragma unroll
      for (int j = 0; j < 4; ++j) {
        int kv = n0 + (wv & 1) * 64 + j * 16 + l16;
        int d = m0 + (wv >> 1) * 64 + i * 16 + quad * 4;
#pragma unroll
        for (int r2 = 0; r2 < 4; ++r2)
          Vt[pidx(d + r2, kv, NROWS / 32)] = f2bf(acc[i][j][r2]);
      }
  } else {
    const int n0 = g * 128;                  // d over 1024
    const int m0 = by * 128;                 // rows over 4096
    const ushort* Bh = which ? Wkh : Wqh;
    const ushort* Bl = which ? Wkl : Wql;
    direct_gemm<true, DDIM / 32>(Xh, Xl, Bh, Bl, m0, n0, acc);
    const float scale = which ? 1.0f : 0.03125f;  // fold 1/sqrt(1024) into Q
    ushort* H = which ? Kh : Qh;
    ushort* L = which ? Kl : Ql;
#pragma unroll
    for (int i = 0; i < 4; ++i)
#pragma unroll
      for (int j = 0; j < 4; ++j) {
        int col = n0 + (wv & 1) * 64 + j * 16 + l16;
        int rw = m0 + (wv >> 1) * 64 + i * 16 + quad * 4;
#pragma unroll
        for (int r2 = 0; r2 < 4; ++r2) {
          float v = acc[i][j][r2] * scale;
          ushort h = f2bf(v);
          size_t o = pidx(rw + r2, col, DDIM / 32);
          H[o] = h;
          L[o] = f2bf(v - bf2f(h));
        }
      }
  }
}

// ---------- S = Q*K^T (split), LDS-free, barrier-free ----------
__global__ __launch_bounds__(256) void gemm_s(const ushort* __restrict__ Qh, const ushort* __restrict__ Ql,
                                              const ushort* __restrict__ Kh, const ushort* __restrict__ Kl,
                                              float* __restrict__ S) {
  const int n0 = blockIdx.x * 128, m0 = blockIdx.y * 128;
  const int t = threadIdx.x;
  const int wv = t >> 6, ln = t & 63;
  const int quad = ln >> 4, l16 = ln & 15;

  f32x4 acc[4][4];
#pragma unroll
  for (int i = 0; i < 4; ++i)
#pragma unroll
    for (int j = 0; j < 4; ++j) acc[i][j] = (f32x4){0.f, 0.f, 0.f, 0.f};

  direct_gemm<true, DDIM / 32>(Qh, Ql, Kh, Kl, m0, n0, acc);

#pragma unroll
  for (int i = 0; i < 4; ++i)
#pragma unroll
    for (int j = 0; j < 4; ++j) {
      int col = n0 + (wv & 1) * 64 + j * 16 + l16;
      int rw = m0 + (wv >> 1) * 64 + i * 16 + quad * 4;
#pragma unroll
      for (int r2 = 0; r2 < 4; ++r2)
        S[(size_t)(rw + r2) * NROWS + col] = acc[i][j][r2];
    }
}

// ---------- softmax: row of S (fp32) -> PACKED bf16 P ----------
__global__ __launch_bounds__(256) void softmax_pack(const float* __restrict__ S,
                                                    ushort* __restrict__ P) {
  const int row = blockIdx.x, t = threadIdx.x;
  const float* Sr = S + (size_t)row * NROWS;
  const float4* S4 = (const float4*)Sr;
  float4 v[4];
  float mx = -3.4e38f;
#pragma unroll
  for (int c = 0; c < 4; ++c) {
    v[c] = S4[c * 256 + t];
    mx = fmaxf(mx, fmaxf(fmaxf(v[c].x, v[c].y), fmaxf(v[c].z, v[c].w)));
  }
  __shared__ float red[4];
  for (int o = 32; o >= 1; o >>= 1) mx = fmaxf(mx, __shfl_xor(mx, o));
  int wv = t >> 6, ln = t & 63;
  if (ln == 0) red[wv] = mx;
  __syncthreads();
  mx = fmaxf(fmaxf(red[0], red[1]), fmaxf(red[2], red[3]));
  float s = 0.f;
#pragma unroll
  for (int c = 0; c < 4; ++c) {
    v[c].x = __expf(v[c].x - mx);
    v[c].y = __expf(v[c].y - mx);
    v[c].z = __expf(v[c].z - mx);
    v[c].w = __expf(v[c].w - mx);
    s += v[c].x + v[c].y + v[c].z + v[c].w;
  }
  for (int o = 32; o >= 1; o >>= 1) s += __shfl_xor(s, o);
  __syncthreads();
  if (ln == 0) red[wv] = s;
  __syncthreads();
  s = red[0] + red[1] + red[2] + red[3];
  float inv = 1.f / s;
#pragma unroll
  for (int c = 0; c < 4; ++c) {
    ushort4 h;
    h.x = f2bf(v[c].x * inv);
    h.y = f2bf(v[c].y * inv);
    h.z = f2bf(v[c].z * inv);
    h.w = f2bf(v[c].w * inv);
    int c0 = 1024 * c + 4 * t;            // 4 consecutive cols, 8B-aligned in packed space
    *(ushort4*)(P + pidx(row, c0, NROWS / 32)) = h;
  }
}

// ---------- Out = P*V, LDS-free, barrier-free; BM=128 (256 blocks, 16 MFMA : 8 loads) ----------
__global__ __launch_bounds__(256) void gemm_pv(const ushort* __restrict__ P,
                                               const ushort* __restrict__ Vt,
                                               float* __restrict__ Out) {
  const int n0 = blockIdx.x * 128, m0 = blockIdx.y * 128;
  const int t = threadIdx.x;
  const int wv = t >> 6, ln = t & 63;
  const int quad = ln >> 4, l16 = ln & 15;

  f32x4 acc[4][4];
#pragma unroll
  for (int i = 0; i < 4; ++i)
#pragma unroll
    for (int j = 0; j < 4; ++j) acc[i][j] = (f32x4){0.f, 0.f, 0.f, 0.f};

  direct_gemm<false, NROWS / 32>(P, nullptr, Vt, nullptr, m0, n0, acc);

#pragma unroll
  for (int i = 0; i < 4; ++i)
#pragma unroll
    for (int j = 0; j < 4; ++j) {
      int col = n0 + (wv & 1) * 64 + j * 16 + l16;
      int rw = m0 + (wv >> 1) * 64 + i * 16 + quad * 4;
#pragma unroll
      for (int r2 = 0; r2 < 4; ++r2)
        Out[(size_t)(rw + r2) * DDIM + col] = acc[i][j][r2];
    }
}

extern "C" void kernel_launch(void* const* d_in, const int* in_sizes, int n_in,
                              void* d_out, int out_size, void* d_ws, size_t ws_size,
                              hipStream_t stream) {
  const float* x  = (const float*)d_in[0];
  const float* wq = (const float*)d_in[1];
  const float* wk = (const float*)d_in[2];
  const float* wv = (const float*)d_in[3];
  char* ws = (char*)d_ws;
  const size_t MB = 1u << 20;

  // Workspace map (peak 104 MiB):
  ushort* Vt  = (ushort*)(ws + 0);        // 0-8   packed, alive through pv
  ushort* Qh  = (ushort*)(ws + 8 * MB);   // 8-40  packed Q/K planes, dead after gemm_s
  ushort* Ql  = (ushort*)(ws + 16 * MB);
  ushort* Kh  = (ushort*)(ws + 24 * MB);
  ushort* Kl  = (ushort*)(ws + 32 * MB);
  ushort* Pp  = (ushort*)(ws + 8 * MB);   // 8-40  packed P (aliases dead Q/K)
  ushort* Xh  = (ushort*)(ws + 40 * MB);  // 40-56 packed X planes (dead after qkv)
  ushort* Xl  = (ushort*)(ws + 48 * MB);
  ushort* Wqh = (ushort*)(ws + 56 * MB);  // 56-66 packed W^T planes (dead after qkv)
  ushort* Wql = (ushort*)(ws + 58 * MB);
  ushort* Wkh = (ushort*)(ws + 60 * MB);
  ushort* Wkl = (ushort*)(ws + 62 * MB);
  ushort* Wvh = (ushort*)(ws + 64 * MB);
  float*  S   = (float*)(ws + 40 * MB);   // 40-104 (overwrites dead X/W)
  float*  Out = (float*)d_out;

  prep<<<4096, 256, 0, stream>>>(x, wq, wk, wv, Xh, Xl, Wqh, Wql, Wkh, Wkl, Wvh);
  gemm_qkv<<<dim3(24, 32), 256, 0, stream>>>(Xh, Xl, Wqh, Wql, Wkh, Wkl, Wvh,
                                             Qh, Ql, Kh, Kl, Vt);
  gemm_s<<<dim3(32, 32), 256, 0, stream>>>(Qh, Ql, Kh, Kl, S);
  softmax_pack<<<NROWS, 256, 0, stream>>>(S, Pp);
  gemm_pv<<<dim3(8, 32), 256, 0, stream>>>(Pp, Vt, Out);
}

// Round 2
// 317.184 us; speedup vs baseline: 1.0928x; 1.0899x over previous
//
#include <hip/hip_runtime.h>
#include <math.h>

#define NROWS 4096
#define DDIM  1024

typedef __attribute__((ext_vector_type(8))) short short8;
typedef __attribute__((ext_vector_type(4))) float f32x4;

// ---------- bf16 helpers (manual RNE) ----------
__device__ __forceinline__ ushort f2bf(float v) {
  union { float f; uint32_t u; } c; c.f = v;
  uint32_t u = c.u;
  uint32_t lsb = (u >> 16) & 1u;
  u += 0x7fffu + lsb;
  return (ushort)(u >> 16);
}
__device__ __forceinline__ float bf2f(ushort h) {
  union { uint32_t u; float f; } c; c.u = ((uint32_t)h) << 16;
  return c.f;
}

// ---------- packed-fragment layout ----------
// Matrix [R][C] bf16 stored as 16x32 tiles of 1KB: tile T = (r>>4)*ldt + (c>>5)
// (ldt = C/32). Within tile: ushort index = ((c>>3)&3)*128 + (r&15)*8 + (c&7).
// A wave's MFMA fragment (rows r0..r0+15, cols c0..c0+31) is then the 1KB at
// T*512, lane ln reading 16B at T*512 + ln*8  (ln = quad*16 + l16).
__device__ __forceinline__ size_t pidx(int r, int c, int ldt) {
  return ((size_t)((r >> 4) * ldt + (c >> 5))) * 512 +
         ((c >> 3) & 3) * 128 + (r & 15) * 8 + (c & 7);
}

// ---------- prep: split x + transpose/split 3 weights, ALL outputs packed ----------
__global__ __launch_bounds__(256) void prep(const float* __restrict__ x,
                                            const float* __restrict__ wq,
                                            const float* __restrict__ wk,
                                            const float* __restrict__ wv,
                                            ushort* Xh, ushort* Xl,
                                            ushort* Wqh, ushort* Wql,
                                            ushort* Wkh, ushort* Wkl, ushort* Wvh) {
  __shared__ float tl[32][33];
  const int b = blockIdx.x, t = threadIdx.x;
  if (b < 1024) {
    const float4* src = (const float4*)x;
#pragma unroll
    for (int r = 0; r < 4; ++r) {
      int i = b * 1024 + r * 256 + t;       // float4 index over [4096][256]
      int row = i >> 8;
      int c = (i & 255) << 2;               // 4-aligned column
      float4 v = src[i];
      ushort4 h, l;
      h.x = f2bf(v.x); l.x = f2bf(v.x - bf2f(h.x));
      h.y = f2bf(v.y); l.y = f2bf(v.y - bf2f(h.y));
      h.z = f2bf(v.z); l.z = f2bf(v.z - bf2f(h.z));
      h.w = f2bf(v.w); l.w = f2bf(v.w - bf2f(h.w));
      size_t o = pidx(row, c, DDIM / 32);   // (c&7)∈{0,4} -> 8B aligned
      *(ushort4*)(Xh + o) = h;
      *(ushort4*)(Xl + o) = l;
    }
  } else {
    const int z = (b - 1024) >> 10;
    const int tile = (b - 1024) & 1023;
    const float* src = z == 0 ? wq : (z == 1 ? wk : wv);
    ushort* dh = z == 0 ? Wqh : (z == 1 ? Wkh : Wvh);
    ushort* dl = z == 0 ? Wql : (z == 1 ? Wkl : nullptr);
    const int r0 = (tile >> 5) * 32;
    const int c0 = (tile & 31) * 32;
    const int tx = t & 31, ty = t >> 5;
    for (int i = ty; i < 32; i += 8)
      tl[i][tx] = src[(size_t)(r0 + i) * DDIM + c0 + tx];
    __syncthreads();
    for (int i = ty; i < 32; i += 8) {
      float v = tl[tx][i];                  // = W[r0+tx][c0+i]
      ushort h = f2bf(v);
      size_t o = pidx(c0 + i, r0 + tx, DDIM / 32);  // W^T[c0+i][r0+tx], packed
      dh[o] = h;
      if (dl) dl[o] = f2bf(v - bf2f(h));
    }
  }
}

// ---------- LDS-free, barrier-free direct packed-fragment GEMM core ----------
// Software-pipelined: fragment-set for step s+1 is loaded while step s's MFMAs
// issue (distance-1 register double-buffer; static indices only).
template <bool SPLIT, int KT>
__device__ __forceinline__ void direct_gemm(const ushort* __restrict__ Ah,
                                            const ushort* __restrict__ Al,
                                            const ushort* __restrict__ Bh,
                                            const ushort* __restrict__ Bl,
                                            int m0, int n0, f32x4 (*acc)[4]) {
  const int t = threadIdx.x;
  const int wv = t >> 6, ln = t & 63;
  const int arb = (wv >> 1) * 64, crb = (wv & 1) * 64;
  const int ra = (m0 + arb) >> 4;           // A tile-row base (frags ra..ra+3)
  const int rb = (n0 + crb) >> 4;
  const uint ts = (uint)KT * 512u;          // tile-row stride in ushorts (fits u32)

  uint oA[4], oB[4];
#pragma unroll
  for (int i = 0; i < 4; ++i) oA[i] = (uint)(ra + i) * ts + (uint)ln * 8u;
#pragma unroll
  for (int j = 0; j < 4; ++j) oB[j] = (uint)(rb + j) * ts + (uint)ln * 8u;

  short8 ah0[4], al0[4], bh0[4], bl0[4];
  short8 ah1[4], al1[4], bh1[4], bl1[4];

#define DG_LOAD(sidx, AH, AL, BH, BL)                                        \
  {                                                                          \
    uint so_ = (uint)(sidx)*512u;                                            \
    _Pragma("unroll") for (int i_ = 0; i_ < 4; ++i_) {                       \
      AH[i_] = *(const short8*)(Ah + oA[i_] + so_);                          \
      if constexpr (SPLIT) AL[i_] = *(const short8*)(Al + oA[i_] + so_);     \
    }                                                                        \
    _Pragma("unroll") for (int j_ = 0; j_ < 4; ++j_) {                       \
      BH[j_] = *(const short8*)(Bh + oB[j_] + so_);                          \
      if constexpr (SPLIT) BL[j_] = *(const short8*)(Bl + oB[j_] + so_);     \
    }                                                                        \
  }

#define DG_MFMA(AH, AL, BH, BL)                                              \
  {                                                                          \
    __builtin_amdgcn_s_setprio(1);                                           \
    _Pragma("unroll") for (int j_ = 0; j_ < 4; ++j_) {                       \
      _Pragma("unroll") for (int i_ = 0; i_ < 4; ++i_) {                     \
        acc[i_][j_] = __builtin_amdgcn_mfma_f32_16x16x32_bf16(               \
            AH[i_], BH[j_], acc[i_][j_], 0, 0, 0);                           \
        if constexpr (SPLIT) {                                               \
          acc[i_][j_] = __builtin_amdgcn_mfma_f32_16x16x32_bf16(             \
              AH[i_], BL[j_], acc[i_][j_], 0, 0, 0);                         \
          acc[i_][j_] = __builtin_amdgcn_mfma_f32_16x16x32_bf16(             \
              AL[i_], BH[j_], acc[i_][j_], 0, 0, 0);                         \
        }                                                                    \
      }                                                                      \
    }                                                                        \
    __builtin_amdgcn_s_setprio(0);                                           \
  }

  DG_LOAD(0, ah0, al0, bh0, bl0);
#pragma unroll 1
  for (int s = 0; s < KT - 2; s += 2) {
    DG_LOAD(s + 1, ah1, al1, bh1, bl1);
    DG_MFMA(ah0, al0, bh0, bl0);
    DG_LOAD(s + 2, ah0, al0, bh0, bl0);
    DG_MFMA(ah1, al1, bh1, bl1);
  }
  DG_LOAD(KT - 1, ah1, al1, bh1, bl1);
  DG_MFMA(ah0, al0, bh0, bl0);
  DG_MFMA(ah1, al1, bh1, bl1);

#undef DG_LOAD
#undef DG_MFMA
}

// ---------- fused QKV: direct-packed, no LDS, no barriers; XCD-chunked swizzle ----------
__global__ __launch_bounds__(256) void gemm_qkv(const ushort* __restrict__ Xh,
                                                const ushort* __restrict__ Xl,
                                                const ushort* __restrict__ Wqh, const ushort* __restrict__ Wql,
                                                const ushort* __restrict__ Wkh, const ushort* __restrict__ Wkl,
                                                const ushort* __restrict__ Wvh,
                                                ushort* Qh, ushort* Ql, ushort* Kh, ushort* Kl, ushort* Vt) {
  // grid (24,32) = 768 blocks; dispatch id -> XCD = id%8. Give each XCD 96
  // contiguous wgs (4 full by-rows): X panels shared, W set streams.
  const int id = blockIdx.y * 24 + blockIdx.x;
  const int wg = (id & 7) * 96 + (id >> 3);
  const int bx = wg % 24, by = wg / 24;
  const int which = bx % 3;
  const int g = bx / 3;                      // 0..7 (d_out slice)
  const int t = threadIdx.x;
  const int wv = t >> 6, ln = t & 63;
  const int quad = ln >> 4, l16 = ln & 15;

  f32x4 acc[4][4];
#pragma unroll
  for (int i = 0; i < 4; ++i)
#pragma unroll
    for (int j = 0; j < 4; ++j) acc[i][j] = (f32x4){0.f, 0.f, 0.f, 0.f};

  if (which == 2) {
    // Vt[d][kv] = sum_k WvT[d][k] * X[kv][k]  (= V[kv][d]) -> packed, ldt = 4096/32
    const int m0 = g * 128;                  // d over 1024
    const int n0 = by * 128;                 // kv over 4096
    direct_gemm<false, DDIM / 32>(Wvh, nullptr, Xh, nullptr, m0, n0, acc);
#pragma unroll
    for (int i = 0; i < 4; ++i)
#pragma unroll
      for (int j = 0; j < 4; ++j) {
        int kv = n0 + (wv & 1) * 64 + j * 16 + l16;
        int d = m0 + (wv >> 1) * 64 + i * 16 + quad * 4;
#pragma unroll
        for (int r2 = 0; r2 < 4; ++r2)
          Vt[pidx(d + r2, kv, NROWS / 32)] = f2bf(acc[i][j][r2]);
      }
  } else {
    const int n0 = g * 128;                  // d over 1024
    const int m0 = by * 128;                 // rows over 4096
    const ushort* Bh = which ? Wkh : Wqh;
    const ushort* Bl = which ? Wkl : Wql;
    direct_gemm<true, DDIM / 32>(Xh, Xl, Bh, Bl, m0, n0, acc);
    const float scale = which ? 1.0f : 0.03125f;  // fold 1/sqrt(1024) into Q
    ushort* H = which ? Kh : Qh;
    ushort* L = which ? Kl : Ql;
#pragma unroll
    for (int i = 0; i < 4; ++i)
#pragma unroll
      for (int j = 0; j < 4; ++j) {
        int col = n0 + (wv & 1) * 64 + j * 16 + l16;
        int rw = m0 + (wv >> 1) * 64 + i * 16 + quad * 4;
#pragma unroll
        for (int r2 = 0; r2 < 4; ++r2) {
          float v = acc[i][j][r2] * scale;
          ushort h = f2bf(v);
          size_t o = pidx(rw + r2, col, DDIM / 32);
          H[o] = h;
          L[o] = f2bf(v - bf2f(h));
        }
      }
  }
}

// ---------- S = Q*K^T (split), LDS-free, barrier-free; XCD 2D-chunked swizzle ----------
__global__ __launch_bounds__(256) void gemm_s(const ushort* __restrict__ Qh, const ushort* __restrict__ Ql,
                                              const ushort* __restrict__ Kh, const ushort* __restrict__ Kl,
                                              float* __restrict__ S) {
  // grid 32x32 = 1024; XCD = bid%8. Each XCD: 8-row x 16-col region,
  // row-fastest order -> 8 Q-panels (4MB) stay L2-resident, K streams.
  const int bid = blockIdx.y * 32 + blockIdx.x;
  const int xcd = bid & 7, local = bid >> 3;
  const int band = xcd >> 1, half = xcd & 1;
  const int row_l = local & 7, col_l = local >> 3;
  const int m0 = (band * 8 + row_l) * 128;
  const int n0 = (half * 16 + col_l) * 128;
  const int t = threadIdx.x;
  const int wv = t >> 6, ln = t & 63;
  const int quad = ln >> 4, l16 = ln & 15;

  f32x4 acc[4][4];
#pragma unroll
  for (int i = 0; i < 4; ++i)
#pragma unroll
    for (int j = 0; j < 4; ++j) acc[i][j] = (f32x4){0.f, 0.f, 0.f, 0.f};

  direct_gemm<true, DDIM / 32>(Qh, Ql, Kh, Kl, m0, n0, acc);

#pragma unroll
  for (int i = 0; i < 4; ++i)
#pragma unroll
    for (int j = 0; j < 4; ++j) {
      int col = n0 + (wv & 1) * 64 + j * 16 + l16;
      int rw = m0 + (wv >> 1) * 64 + i * 16 + quad * 4;
#pragma unroll
      for (int r2 = 0; r2 < 4; ++r2)
        S[(size_t)(rw + r2) * NROWS + col] = acc[i][j][r2];
    }
}

// ---------- softmax: row of S (fp32) -> PACKED bf16 P ----------
__global__ __launch_bounds__(256) void softmax_pack(const float* __restrict__ S,
                                                    ushort* __restrict__ P) {
  const int row = blockIdx.x, t = threadIdx.x;
  const float* Sr = S + (size_t)row * NROWS;
  const float4* S4 = (const float4*)Sr;
  float4 v[4];
  float mx = -3.4e38f;
#pragma unroll
  for (int c = 0; c < 4; ++c) {
    v[c] = S4[c * 256 + t];
    mx = fmaxf(mx, fmaxf(fmaxf(v[c].x, v[c].y), fmaxf(v[c].z, v[c].w)));
  }
  __shared__ float red[4];
  for (int o = 32; o >= 1; o >>= 1) mx = fmaxf(mx, __shfl_xor(mx, o));
  int wv = t >> 6, ln = t & 63;
  if (ln == 0) red[wv] = mx;
  __syncthreads();
  mx = fmaxf(fmaxf(red[0], red[1]), fmaxf(red[2], red[3]));
  float s = 0.f;
#pragma unroll
  for (int c = 0; c < 4; ++c) {
    v[c].x = __expf(v[c].x - mx);
    v[c].y = __expf(v[c].y - mx);
    v[c].z = __expf(v[c].z - mx);
    v[c].w = __expf(v[c].w - mx);
    s += v[c].x + v[c].y + v[c].z + v[c].w;
  }
  for (int o = 32; o >= 1; o >>= 1) s += __shfl_xor(s, o);
  __syncthreads();
  if (ln == 0) red[wv] = s;
  __syncthreads();
  s = red[0] + red[1] + red[2] + red[3];
  float inv = 1.f / s;
#pragma unroll
  for (int c = 0; c < 4; ++c) {
    ushort4 h;
    h.x = f2bf(v[c].x * inv);
    h.y = f2bf(v[c].y * inv);
    h.z = f2bf(v[c].z * inv);
    h.w = f2bf(v[c].w * inv);
    int c0 = 1024 * c + 4 * t;            // 4 consecutive cols, 8B-aligned in packed space
    *(ushort4*)(P + pidx(row, c0, NROWS / 32)) = h;
  }
}

// ---------- Out = P*V, LDS-free, barrier-free; BM=128 ----------
// grid (8,32): dispatch id%8 == bx -> each XCD naturally owns one Vt stripe.
__global__ __launch_bounds__(256) void gemm_pv(const ushort* __restrict__ P,
                                               const ushort* __restrict__ Vt,
                                               float* __restrict__ Out) {
  const int n0 = blockIdx.x * 128, m0 = blockIdx.y * 128;
  const int t = threadIdx.x;
  const int wv = t >> 6, ln = t & 63;
  const int quad = ln >> 4, l16 = ln & 15;

  f32x4 acc[4][4];
#pragma unroll
  for (int i = 0; i < 4; ++i)
#pragma unroll
    for (int j = 0; j < 4; ++j) acc[i][j] = (f32x4){0.f, 0.f, 0.f, 0.f};

  direct_gemm<false, NROWS / 32>(P, nullptr, Vt, nullptr, m0, n0, acc);

#pragma unroll
  for (int i = 0; i < 4; ++i)
#pragma unroll
    for (int j = 0; j < 4; ++j) {
      int col = n0 + (wv & 1) * 64 + j * 16 + l16;
      int rw = m0 + (wv >> 1) * 64 + i * 16 + quad * 4;
#pragma unroll
      for (int r2 = 0; r2 < 4; ++r2)
        Out[(size_t)(rw + r2) * DDIM + col] = acc[i][j][r2];
    }
}

extern "C" void kernel_launch(void* const* d_in, const int* in_sizes, int n_in,
                              void* d_out, int out_size, void* d_ws, size_t ws_size,
                              hipStream_t stream) {
  const float* x  = (const float*)d_in[0];
  const float* wq = (const float*)d_in[1];
  const float* wk = (const float*)d_in[2];
  const float* wv = (const float*)d_in[3];
  char* ws = (char*)d_ws;
  const size_t MB = 1u << 20;

  // Workspace map (peak 104 MiB):
  ushort* Vt  = (ushort*)(ws + 0);        // 0-8   packed, alive through pv
  ushort* Qh  = (ushort*)(ws + 8 * MB);   // 8-40  packed Q/K planes, dead after gemm_s
  ushort* Ql  = (ushort*)(ws + 16 * MB);
  ushort* Kh  = (ushort*)(ws + 24 * MB);
  ushort* Kl  = (ushort*)(ws + 32 * MB);
  ushort* Pp  = (ushort*)(ws + 8 * MB);   // 8-40  packed P (aliases dead Q/K)
  ushort* Xh  = (ushort*)(ws + 40 * MB);  // 40-56 packed X planes (dead after qkv)
  ushort* Xl  = (ushort*)(ws + 48 * MB);
  ushort* Wqh = (ushort*)(ws + 56 * MB);  // 56-66 packed W^T planes (dead after qkv)
  ushort* Wql = (ushort*)(ws + 58 * MB);
  ushort* Wkh = (ushort*)(ws + 60 * MB);
  ushort* Wkl = (ushort*)(ws + 62 * MB);
  ushort* Wvh = (ushort*)(ws + 64 * MB);
  float*  S   = (float*)(ws + 40 * MB);   // 40-104 (overwrites dead X/W)
  float*  Out = (float*)d_out;

  prep<<<4096, 256, 0, stream>>>(x, wq, wk, wv, Xh, Xl, Wqh, Wql, Wkh, Wkl, Wvh);
  gemm_qkv<<<dim3(24, 32), 256, 0, stream>>>(Xh, Xl, Wqh, Wql, Wkh, Wkl, Wvh,
                                             Qh, Ql, Kh, Kl, Vt);
  gemm_s<<<dim3(32, 32), 256, 0, stream>>>(Qh, Ql, Kh, Kl, S);
  softmax_pack<<<NROWS, 256, 0, stream>>>(S, Pp);
  gemm_pv<<<dim3(8, 32), 256, 0, stream>>>(Pp, Vt, Out);
}